// Round 10
// baseline (239.887 us; speedup 1.0000x reference)
//
#include <hip/hip_runtime.h>
#include <math.h>

#define BATCH 64
#define DIM   640
#define MSP   100        // spatial M = 10*10
#define TILE  64
#define NT    10         // DIM / TILE
#define NPAIR 55         // NT*(NT+1)/2 upper-tri tile pairs
#define PTRI  205120     // DIM*(DIM+1)/2
#define EPSV  1e-5f
#define GRID  440        // 440 x 8 tiles = 3520; 2 blk/CU (512 slots) -> all co-resident
#define TPB   8          // tiles per block

// ws float-region offsets (floats)
#define WS_D 0
#define WS_S 40960
#define WS_G 81920            // 64 grand accumulators (raw sums)
#define WS_C 81984            // software-barrier counter (unsigned)
// byte offset of swizzled bf16 xb
#define XB_OFF 328192ull      // 2560 panels x 2048 shorts = 10,485,760 B; ws ~10.8 MB

// xb swizzle: panel = 16 rows x 128 k, stored [c = ks*4+lq][lm = row%16][8 halves]
// -> a gram wave's frag load reads ONE contiguous 1024B block (R7-proven).

typedef __attribute__((ext_vector_type(8))) short short8;
typedef __attribute__((ext_vector_type(4))) float f32x4;
typedef __attribute__((ext_vector_type(2))) __fp16 fp16x2;   // cvt_pkrtz result type

__device__ __forceinline__ short f2bf(float f) {
    union { float f; unsigned u; } x; x.f = f;
    unsigned r = x.u + 0x7fffu + ((x.u >> 16) & 1u);
    return (short)(r >> 16);
}
__device__ __forceinline__ float bf2f(short h) {
    union { unsigned u; float f; } x; x.u = ((unsigned)(unsigned short)h) << 16;
    return x.f;
}
__device__ __forceinline__ void decode_pair(int u, int& ti, int& tj) {
    ti = 0;
    while (u >= NT - ti) { u -= NT - ti; ++ti; }
    tj = ti + u;
}

// bf16 convert + swizzle + norms (from ROUNDED values so the diagonal
// d_i+d_i-2G_ii cancels exactly vs the bf16 MFMA Gram). S/G/counter are
// zeroed by hipMemsetAsync before this kernel.
__global__ __launch_bounds__(256) void k_prep(const float* __restrict__ x,
                                              float* __restrict__ ws) {
    short* xb = (short*)((char*)ws + XB_OFF);
    const int t = threadIdx.x;
    const int rr = t >> 4, cc = t & 15;
    const int row = blockIdx.x * 16 + rr;          // 0..40959
    const int k0 = cc * 8;
    const float* src = x + (size_t)row * MSP;

    float v[8];
#pragma unroll
    for (int e = 0; e < 8; ++e) v[e] = 0.f;
    if (k0 <= 88) {
        float4 u0 = *(const float4*)(src + k0);
        float4 u1 = *(const float4*)(src + k0 + 4);
        v[0] = u0.x; v[1] = u0.y; v[2] = u0.z; v[3] = u0.w;
        v[4] = u1.x; v[5] = u1.y; v[6] = u1.z; v[7] = u1.w;
    } else if (k0 == 96) {                         // only 96..99 valid (no OOB read)
        float4 u0 = *(const float4*)(src + 96);
        v[0] = u0.x; v[1] = u0.y; v[2] = u0.z; v[3] = u0.w;
    }

    short8 h; float s = 0.f;
#pragma unroll
    for (int e = 0; e < 8; ++e) {
        short hb = f2bf(v[e]);
        float vr = bf2f(hb);
        s += vr * vr;
        h[e] = hb;
    }
    *(short8*)(xb + (size_t)blockIdx.x * 2048 + cc * 128 + rr * 8) = h;

    s += __shfl_xor(s, 1); s += __shfl_xor(s, 2);
    s += __shfl_xor(s, 4); s += __shfl_xor(s, 8);
    if (cc == 0) ws[WS_D + row] = s;
}

// Device-wide software barrier: all GRID blocks are co-resident (440 <= 512
// slots at 2 blk/CU). Release: syncthreads drains the block, thread-0 fence +
// device-scope atomic arrive. Acquire: spin on device-scope load, fence, sync.
__device__ __forceinline__ void grid_barrier(unsigned* cnt, int tid) {
    __syncthreads();
    if (tid == 0) {
        __threadfence();
        atomicAdd(cnt, 1u);
        while (__hip_atomic_load(cnt, __ATOMIC_ACQUIRE, __HIP_MEMORY_SCOPE_AGENT) < GRID)
            __builtin_amdgcn_s_sleep(2);
        __threadfence();
    }
    __syncthreads();
}

// Persistent fused kernel: phase A computes 8 dcov tiles (MFMA Gram ->
// sqrt-dcov packed fp16 in REGISTERS) + S/grand sums via global atomics;
// software grid barrier; phase B applies centering + direct triu stores.
// No LDS, no tile materialization, one launch.
__global__ __launch_bounds__(256, 2) void k_fused(const float* __restrict__ tsc,
                                                  float* __restrict__ ws,
                                                  float* __restrict__ out) {
    short* xb = (short*)((char*)ws + XB_OFF);
    const int tid = threadIdx.x;

    const float scale = expf(tsc[0]);
    const int wave = tid >> 6, lane = tid & 63;
    const int lm = lane & 15, lq = lane >> 4;
    const int r0 = (wave >> 1) * 32, c0 = (wave & 1) * 32;
    const int tbase = blockIdx.x * TPB;

    uint4 tr[TPB][2];

    // ---- phase A ----
#pragma unroll
    for (int s8 = 0; s8 < TPB; ++s8) {
        const int u = tbase + s8;
        const int b = u / NPAIR;
        int ti, tj;
        decode_pair(u - b * NPAIR, ti, tj);
        const int i0 = ti * TILE, j0 = tj * TILE;
        const float* dn = ws + WS_D + b * DIM;
        float* S = ws + WS_S + b * DIM;

        const short* pa = xb + (size_t)(b * 40 + ((i0 + r0) >> 4)) * 2048 + lq * 128 + lm * 8;
        const short* pb = xb + (size_t)(b * 40 + ((j0 + c0) >> 4)) * 2048 + lq * 128 + lm * 8;

        f32x4 acc[2][2] = {};
#pragma unroll
        for (int ks = 0; ks < 4; ++ks) {
            short8 a0 = *(const short8*)(pa + ks * 512);
            short8 a1 = *(const short8*)(pa + 2048 + ks * 512);
            short8 b0 = *(const short8*)(pb + ks * 512);
            short8 b1 = *(const short8*)(pb + 2048 + ks * 512);
            acc[0][0] = __builtin_amdgcn_mfma_f32_16x16x32_bf16(a0, b0, acc[0][0], 0, 0, 0);
            acc[0][1] = __builtin_amdgcn_mfma_f32_16x16x32_bf16(a0, b1, acc[0][1], 0, 0, 0);
            acc[1][0] = __builtin_amdgcn_mfma_f32_16x16x32_bf16(a1, b0, acc[1][0], 0, 0, 0);
            acc[1][1] = __builtin_amdgcn_mfma_f32_16x16x32_bf16(a1, b1, acc[1][1], 0, 0, 0);
        }

        float di[2][4], dj[2];
#pragma unroll
        for (int a = 0; a < 2; ++a)
#pragma unroll
            for (int r = 0; r < 4; ++r) di[a][r] = dn[i0 + r0 + 16 * a + lq * 4 + r];
#pragma unroll
        for (int bb = 0; bb < 2; ++bb) dj[bb] = dn[j0 + c0 + 16 * bb + lm];

        float rp[2][4] = {}, cp[2] = {};
#pragma unroll
        for (int a = 0; a < 2; ++a) {
            unsigned wd[4];
#pragma unroll
            for (int bb = 0; bb < 2; ++bb)
#pragma unroll
                for (int p = 0; p < 2; ++p) {
                    float d0 = di[a][2 * p]     + dj[bb];
                    float d1 = di[a][2 * p + 1] + dj[bb];
                    float v0 = __builtin_amdgcn_sqrtf(
                        fmaf(scale, fmaxf(fmaf(-2.f, acc[a][bb][2 * p],     d0), 0.f), EPSV));
                    float v1 = __builtin_amdgcn_sqrtf(
                        fmaf(scale, fmaxf(fmaf(-2.f, acc[a][bb][2 * p + 1], d1), 0.f), EPSV));
                    rp[a][2 * p] += v0; rp[a][2 * p + 1] += v1; cp[bb] += v0 + v1;
                    union { fp16x2 h; unsigned u; } cv;
                    cv.h = __builtin_amdgcn_cvt_pkrtz(v0, v1);
                    wd[bb * 2 + p] = cv.u;
                }
            tr[s8][a].x = wd[0]; tr[s8][a].y = wd[1];
            tr[s8][a].z = wd[2]; tr[s8][a].w = wd[3];
        }

        // row sums: reduce over lm within each 16-lane group, commit lm==0
        float tsum = 0.f;
#pragma unroll
        for (int a = 0; a < 2; ++a)
#pragma unroll
            for (int r = 0; r < 4; ++r) {
                float v = rp[a][r];
                tsum += v;
                v += __shfl_xor(v, 1); v += __shfl_xor(v, 2);
                v += __shfl_xor(v, 4); v += __shfl_xor(v, 8);
                if (lm == 0) atomicAdd(&S[i0 + r0 + 16 * a + lq * 4 + r], v);
            }
        // col sums (skip on diagonal tiles: col==row by symmetry)
        if (ti != tj) {
#pragma unroll
            for (int bb = 0; bb < 2; ++bb) {
                float v = cp[bb];
                v += __shfl_xor(v, 16); v += __shfl_xor(v, 32);
                if (lq == 0) atomicAdd(&S[j0 + c0 + 16 * bb + lm], v);
            }
        }
        // grand total (raw): full-wave butterfly, one atomic per wave
        tsum += __shfl_xor(tsum, 1);  tsum += __shfl_xor(tsum, 2);
        tsum += __shfl_xor(tsum, 4);  tsum += __shfl_xor(tsum, 8);
        tsum += __shfl_xor(tsum, 16); tsum += __shfl_xor(tsum, 32);
        if (lane == 0) atomicAdd(&ws[WS_G + b], (ti == tj ? 1.f : 2.f) * tsum);
    }

    grid_barrier((unsigned*)(ws + WS_C), tid);

    // ---- phase B: centering + triu pack from register-held fp16 tiles ----
    const float inv = 1.f / (float)DIM;

#pragma unroll
    for (int s8 = 0; s8 < TPB; ++s8) {
        const int u = tbase + s8;
        const int b = u / NPAIR;
        int ti, tj;
        decode_pair(u - b * NPAIR, ti, tj);
        const int i0 = ti * TILE, j0 = tj * TILE;
        const bool offd = (ti != tj);
        const float* S = ws + WS_S + b * DIM;
        const float g = ws[WS_G + b] * (inv * inv);
        float* outb = out + (size_t)b * PTRI;

        float ai[2][4]; int ib[2][4];
#pragma unroll
        for (int a = 0; a < 2; ++a)
#pragma unroll
            for (int r = 0; r < 4; ++r) {
                int i = i0 + r0 + 16 * a + 4 * lq + r;
                ai[a][r] = g - S[i] * inv;
                ib[a][r] = i * DIM - (i * (i - 1)) / 2 - i;  // triu row offset minus i
            }
        float bj[2]; int jj[2];
#pragma unroll
        for (int bb = 0; bb < 2; ++bb) {
            int j = j0 + c0 + 16 * bb + lm;
            jj[bb] = j; bj[bb] = -S[j] * inv;
        }

#pragma unroll
        for (int a = 0; a < 2; ++a) {
            unsigned wd[4] = {tr[s8][a].x, tr[s8][a].y, tr[s8][a].z, tr[s8][a].w};
            const int ibase = i0 + r0 + 16 * a + 4 * lq;
#pragma unroll
            for (int bb = 0; bb < 2; ++bb)
#pragma unroll
                for (int p = 0; p < 2; ++p) {
                    union { unsigned uu; fp16x2 h; } cv; cv.uu = wd[bb * 2 + p];
                    float v0 = (float)cv.h.x, v1 = (float)cv.h.y;
                    const int r = 2 * p;
                    if (offd || jj[bb] >= ibase + r)
                        outb[ib[a][r] + jj[bb]] = v0 + ai[a][r] + bj[bb];
                    if (offd || jj[bb] >= ibase + r + 1)
                        outb[ib[a][r + 1] + jj[bb]] = v1 + ai[a][r + 1] + bj[bb];
                }
        }
    }
}

extern "C" void kernel_launch(void* const* d_in, const int* in_sizes, int n_in,
                              void* d_out, int out_size, void* d_ws, size_t ws_size,
                              hipStream_t stream) {
    const float* x = (const float*)d_in[0];
    const float* t = (const float*)d_in[1];
    float* out = (float*)d_out;
    float* ws  = (float*)d_ws;   // needs ~10.8 MB (see layout at top)

    // zero S accumulators, grand accumulators, and the barrier counter
    hipMemsetAsync((char*)ws + (size_t)WS_S * 4, 0,
                   (size_t)(DIM * BATCH + BATCH + 16) * 4, stream);
    k_prep <<<dim3(BATCH * DIM / 16), 256, 0, stream>>>(x, ws);
    k_fused<<<dim3(GRID),             256, 0, stream>>>(t, ws, out);
}